// Round 1
// baseline (5977.021 us; speedup 1.0000x reference)
//
#include <hip/hip_runtime.h>

#define N_USERS 200000
#define N_ITEMS 100000
#define NN      300000        // N_USERS + N_ITEMS
#define DIM     64
#define N_EDGES 9600000
#define BATCH   16384
#define N_LAYERS 3

// ---------------- init: E0 = concat(user_emb, item_emb), zero Enext ----------------
__global__ void copy_init(const float* __restrict__ ue, const float* __restrict__ ie,
                          float* __restrict__ E) {
    const size_t nU = (size_t)N_USERS * DIM / 4;
    const size_t nT = (size_t)NN * DIM / 4;
    const float4* u4 = (const float4*)ue;
    const float4* i4 = (const float4*)ie;
    float4* E4 = (float4*)E;
    size_t stride = (size_t)gridDim.x * blockDim.x;
    for (size_t k = (size_t)blockIdx.x * blockDim.x + threadIdx.x; k < nT; k += stride) {
        E4[k] = (k < nU) ? u4[k] : i4[k - nU];
    }
}

__global__ void zero_buf(float4* __restrict__ p, size_t n4) {
    size_t stride = (size_t)gridDim.x * blockDim.x;
    for (size_t k = (size_t)blockIdx.x * blockDim.x + threadIdx.x; k < n4; k += stride) {
        p[k] = make_float4(0.f, 0.f, 0.f, 0.f);
    }
}

// ---------------- acc init / accumulate at the 2*BATCH target rows ----------------
__global__ void acc_init(const float* __restrict__ E, const int* __restrict__ U,
                         const int* __restrict__ I, float* __restrict__ accU,
                         float* __restrict__ accI) {
    int t = blockIdx.x * blockDim.x + threadIdx.x;   // BATCH*DIM threads
    int b = t >> 6, d = t & 63;
    accU[t] = E[(size_t)U[b] * DIM + d];
    accI[t] = E[(size_t)(N_USERS + I[b]) * DIM + d];
}

__global__ void acc_add(const float* __restrict__ E, const int* __restrict__ U,
                        const int* __restrict__ I, float* __restrict__ accU,
                        float* __restrict__ accI) {
    int t = blockIdx.x * blockDim.x + threadIdx.x;
    int b = t >> 6, d = t & 63;
    accU[t] += E[(size_t)U[b] * DIM + d];
    accI[t] += E[(size_t)(N_USERS + I[b]) * DIM + d];
}

// ---------------- SpMM: one wave per edge, lane = dim ----------------
__global__ void spmm_atomic(const int* __restrict__ rows, const int* __restrict__ cols,
                            const float* __restrict__ vals, const float* __restrict__ Ein,
                            float* __restrict__ Eout) {
    int wave   = (blockIdx.x * blockDim.x + threadIdx.x) >> 6;
    int lane   = threadIdx.x & 63;
    int nwaves = (gridDim.x * blockDim.x) >> 6;
    for (int e = wave; e < N_EDGES; e += nwaves) {
        int   r = rows[e];
        int   c = cols[e];
        float v = vals[e];
        float x = Ein[(size_t)c * DIM + lane];
        atomicAdd(&Eout[(size_t)r * DIM + lane], v * x);
    }
}

// ---------------- final: out[b] = dot(accU[b], accI[b]) / 16 ----------------
__global__ void dot_out(const float* __restrict__ accU, const float* __restrict__ accI,
                        float* __restrict__ out) {
    int t = blockIdx.x * blockDim.x + threadIdx.x;
    int b = t >> 6, lane = threadIdx.x & 63;
    float p = accU[t] * accI[t];
    #pragma unroll
    for (int off = 32; off; off >>= 1) p += __shfl_xor(p, off, 64);
    if (lane == 0) out[b] = p * (1.0f / 16.0f);
}

extern "C" void kernel_launch(void* const* d_in, const int* in_sizes, int n_in,
                              void* d_out, int out_size, void* d_ws, size_t ws_size,
                              hipStream_t stream) {
    const float* ue   = (const float*)d_in[0];
    const float* ie   = (const float*)d_in[1];
    const float* vals = (const float*)d_in[2];
    const int*   rows = (const int*)d_in[3];
    const int*   cols = (const int*)d_in[4];
    const int*   U    = (const int*)d_in[5];
    const int*   I    = (const int*)d_in[6];
    float* out = (float*)d_out;

    char* ws = (char*)d_ws;
    const size_t Ebytes = (size_t)NN * DIM * sizeof(float);   // 76.8 MB
    float* Ecur  = (float*)ws;
    float* Enext = (float*)(ws + Ebytes);
    float* accU  = (float*)(ws + 2 * Ebytes);                  // 4.2 MB
    float* accI  = accU + (size_t)BATCH * DIM;                 // 4.2 MB

    copy_init<<<2048, 256, 0, stream>>>(ue, ie, Ecur);
    acc_init<<<BATCH * DIM / 256, 256, 0, stream>>>(Ecur, U, I, accU, accI);

    for (int l = 0; l < N_LAYERS; ++l) {
        zero_buf<<<2048, 256, 0, stream>>>((float4*)Enext, (size_t)NN * DIM / 4);
        spmm_atomic<<<8192, 256, 0, stream>>>(rows, cols, vals, Ecur, Enext);
        acc_add<<<BATCH * DIM / 256, 256, 0, stream>>>(Enext, U, I, accU, accI);
        float* t = Ecur; Ecur = Enext; Enext = t;
    }

    dot_out<<<BATCH / 4, 256, 0, stream>>>(accU, accI, out);
}

// Round 2
// 1917.824 us; speedup vs baseline: 3.1166x; 3.1166x over previous
//
#include <hip/hip_runtime.h>

#define N_USERS 200000
#define N_ITEMS 100000
#define NN      300000        // N_USERS + N_ITEMS
#define DIM     64
#define N_EDGES 9600000
#define BATCH   16384
#define N_LAYERS 3
#define SCAN_BS 1024          // rows per scan block

// ---------------- init: E0 = concat(user_emb, item_emb) ----------------
__global__ void copy_init(const float* __restrict__ ue, const float* __restrict__ ie,
                          float* __restrict__ E) {
    const size_t nU = (size_t)N_USERS * DIM / 4;
    const size_t nT = (size_t)NN * DIM / 4;
    const float4* u4 = (const float4*)ue;
    const float4* i4 = (const float4*)ie;
    float4* E4 = (float4*)E;
    size_t stride = (size_t)gridDim.x * blockDim.x;
    for (size_t k = (size_t)blockIdx.x * blockDim.x + threadIdx.x; k < nT; k += stride)
        E4[k] = (k < nU) ? u4[k] : i4[k - nU];
}

// ---------------- CSR build ----------------
__global__ void hist_rows(const int* __restrict__ rows, int* __restrict__ cnt) {
    int stride = gridDim.x * blockDim.x;
    for (int e = blockIdx.x * blockDim.x + threadIdx.x; e < N_EDGES; e += stride)
        atomicAdd(&cnt[rows[e]], 1);
}

// exclusive scan within blocks of SCAN_BS; block totals to bsum
__global__ void scan_block(const int* __restrict__ cnt, int* __restrict__ excl,
                           int* __restrict__ bsum) {
    __shared__ int s[SCAN_BS];
    int tid = threadIdx.x;
    int i = blockIdx.x * SCAN_BS + tid;
    int x = (i < NN) ? cnt[i] : 0;
    s[tid] = x;
    __syncthreads();
    for (int off = 1; off < SCAN_BS; off <<= 1) {
        int t = (tid >= off) ? s[tid - off] : 0;
        __syncthreads();
        s[tid] += t;
        __syncthreads();
    }
    if (i < NN) excl[i] = s[tid] - x;
    if (tid == SCAN_BS - 1) bsum[blockIdx.x] = s[tid];
}

// exclusive scan of block sums (nb <= 512), single block of 512
__global__ void scan_bsum(int* __restrict__ bsum, int nb) {
    __shared__ int s[512];
    int tid = threadIdx.x;
    int x = (tid < nb) ? bsum[tid] : 0;
    s[tid] = x;
    __syncthreads();
    for (int off = 1; off < 512; off <<= 1) {
        int t = (tid >= off) ? s[tid - off] : 0;
        __syncthreads();
        s[tid] += t;
        __syncthreads();
    }
    if (tid < nb) bsum[tid] = s[tid] - x;
}

// rowptr[i] = excl[i] + bsum[i/SCAN_BS]; ticket[i] = same; rowptr[NN] = N_EDGES
__global__ void add_offsets(int* __restrict__ rowptr, const int* __restrict__ bsum,
                            int* __restrict__ ticket) {
    int i = blockIdx.x * blockDim.x + threadIdx.x;
    if (i < NN) {
        int v = rowptr[i] + bsum[i >> 10];
        rowptr[i] = v;
        ticket[i] = v;
    }
    if (i == 0) rowptr[NN] = N_EDGES;
}

// scatter edges into row-sorted packed array: epack[pos] = (col, val)
__global__ void scatter_edges(const int* __restrict__ rows, const int* __restrict__ cols,
                              const float* __restrict__ vals, int* __restrict__ ticket,
                              int2* __restrict__ epack) {
    int stride = gridDim.x * blockDim.x;
    for (int e = blockIdx.x * blockDim.x + threadIdx.x; e < N_EDGES; e += stride) {
        int r = rows[e];
        int pos = atomicAdd(&ticket[r], 1);
        epack[pos] = make_int2(cols[e], __float_as_int(vals[e]));
    }
}

// ---------------- SpMM: one wave per row, lane = dim, no atomics ----------------
__global__ void spmm_csr(const int* __restrict__ rowptr, const int2* __restrict__ ep,
                         const float* __restrict__ Ein, float* __restrict__ Eout) {
    int lane = threadIdx.x & 63;
    int w = (int)((blockIdx.x * (size_t)blockDim.x + threadIdx.x) >> 6);
    int row = __builtin_amdgcn_readfirstlane(w);   // wave-uniform -> scalar loads below
    if (row >= NN) return;
    int beg = rowptr[row];
    int end = rowptr[row + 1];
    float acc = 0.f;
    int j = beg;
    for (; j + 4 <= end; j += 4) {
        int2 e0 = ep[j], e1 = ep[j + 1], e2 = ep[j + 2], e3 = ep[j + 3];
        float x0 = Ein[(size_t)e0.x * DIM + lane];
        float x1 = Ein[(size_t)e1.x * DIM + lane];
        float x2 = Ein[(size_t)e2.x * DIM + lane];
        float x3 = Ein[(size_t)e3.x * DIM + lane];
        acc += __int_as_float(e0.y) * x0;
        acc += __int_as_float(e1.y) * x1;
        acc += __int_as_float(e2.y) * x2;
        acc += __int_as_float(e3.y) * x3;
    }
    for (; j < end; ++j) {
        int2 e = ep[j];
        acc += __int_as_float(e.y) * Ein[(size_t)e.x * DIM + lane];
    }
    Eout[(size_t)row * DIM + lane] = acc;
}

// ---------------- acc at the 2*BATCH target rows ----------------
__global__ void acc_init(const float* __restrict__ E, const int* __restrict__ U,
                         const int* __restrict__ I, float* __restrict__ accU,
                         float* __restrict__ accI) {
    int t = blockIdx.x * blockDim.x + threadIdx.x;
    int b = t >> 6, d = t & 63;
    accU[t] = E[(size_t)U[b] * DIM + d];
    accI[t] = E[(size_t)(N_USERS + I[b]) * DIM + d];
}

__global__ void acc_add(const float* __restrict__ E, const int* __restrict__ U,
                        const int* __restrict__ I, float* __restrict__ accU,
                        float* __restrict__ accI) {
    int t = blockIdx.x * blockDim.x + threadIdx.x;
    int b = t >> 6, d = t & 63;
    accU[t] += E[(size_t)U[b] * DIM + d];
    accI[t] += E[(size_t)(N_USERS + I[b]) * DIM + d];
}

// ---------------- final: out[b] = dot(accU[b], accI[b]) / 16 ----------------
__global__ void dot_out(const float* __restrict__ accU, const float* __restrict__ accI,
                        float* __restrict__ out) {
    int t = blockIdx.x * blockDim.x + threadIdx.x;
    int b = t >> 6, lane = threadIdx.x & 63;
    float p = accU[t] * accI[t];
    #pragma unroll
    for (int off = 32; off; off >>= 1) p += __shfl_xor(p, off, 64);
    if (lane == 0) out[b] = p * (1.0f / 16.0f);
}

extern "C" void kernel_launch(void* const* d_in, const int* in_sizes, int n_in,
                              void* d_out, int out_size, void* d_ws, size_t ws_size,
                              hipStream_t stream) {
    const float* ue   = (const float*)d_in[0];
    const float* ie   = (const float*)d_in[1];
    const float* vals = (const float*)d_in[2];
    const int*   rows = (const int*)d_in[3];
    const int*   cols = (const int*)d_in[4];
    const int*   U    = (const int*)d_in[5];
    const int*   I    = (const int*)d_in[6];
    float* out = (float*)d_out;

    char* ws = (char*)d_ws;
    const size_t Ebytes  = (size_t)NN * DIM * sizeof(float);       // 76.8 MB
    const size_t EPbytes = (size_t)N_EDGES * sizeof(int2);         // 76.8 MB
    const size_t ACbytes = (size_t)BATCH * DIM * sizeof(float);    // 4.2 MB
    const size_t RPbytes = ((size_t)(NN + 1) * sizeof(int) + 255) & ~(size_t)255;

    size_t off = 0;
    float* Ecur   = (float*)(ws + off); off += Ebytes;
    float* Enext  = (float*)(ws + off); off += Ebytes;
    int2*  epack  = (int2*)(ws + off);  off += EPbytes;
    float* accU   = (float*)(ws + off); off += ACbytes;
    float* accI   = (float*)(ws + off); off += ACbytes;
    int*   rowptr = (int*)(ws + off);   off += RPbytes;
    int*   cnt    = (int*)(ws + off);   off += RPbytes;            // also reused as ticket
    int*   bsum   = (int*)(ws + off);   off += 512 * sizeof(int);

    const int nScanBlocks = (NN + SCAN_BS - 1) / SCAN_BS;          // 293

    // --- build CSR ---
    hipMemsetAsync(cnt, 0, (size_t)NN * sizeof(int), stream);
    hist_rows<<<4096, 256, 0, stream>>>(rows, cnt);
    scan_block<<<nScanBlocks, SCAN_BS, 0, stream>>>(cnt, rowptr, bsum);
    scan_bsum<<<1, 512, 0, stream>>>(bsum, nScanBlocks);
    add_offsets<<<(NN + 255) / 256, 256, 0, stream>>>(rowptr, bsum, cnt);
    scatter_edges<<<4096, 256, 0, stream>>>(rows, cols, vals, cnt, epack);

    // --- embeddings + propagation ---
    copy_init<<<2048, 256, 0, stream>>>(ue, ie, Ecur);
    acc_init<<<BATCH * DIM / 256, 256, 0, stream>>>(Ecur, U, I, accU, accI);

    const int spmmBlocks = (NN * 64 + 255) / 256;                  // 1 wave per row
    for (int l = 0; l < N_LAYERS; ++l) {
        spmm_csr<<<spmmBlocks, 256, 0, stream>>>(rowptr, epack, Ecur, Enext);
        acc_add<<<BATCH * DIM / 256, 256, 0, stream>>>(Enext, U, I, accU, accI);
        float* t = Ecur; Ecur = Enext; Enext = t;
    }

    dot_out<<<BATCH / 4, 256, 0, stream>>>(accU, accI, out);
}

// Round 3
// 1912.318 us; speedup vs baseline: 3.1255x; 1.0029x over previous
//
#include <hip/hip_runtime.h>

#define N_USERS 200000
#define N_ITEMS 100000
#define NN      300000        // N_USERS + N_ITEMS
#define DIM     64
#define N_EDGES 9600000
#define BATCH   16384
#define N_LAYERS 3
#define SCAN_BS 1024          // rows per scan block
#define BSHIFT  9             // 512 rows per bucket
#define NB      586           // ceil(NN / 512)
#define CHUNK   32768         // edges per bin_pass1 block

// ---------------- init: E0 = concat(user_emb, item_emb) ----------------
__global__ void copy_init(const float* __restrict__ ue, const float* __restrict__ ie,
                          float* __restrict__ E) {
    const size_t nU = (size_t)N_USERS * DIM / 4;
    const size_t nT = (size_t)NN * DIM / 4;
    const float4* u4 = (const float4*)ue;
    const float4* i4 = (const float4*)ie;
    float4* E4 = (float4*)E;
    size_t stride = (size_t)gridDim.x * blockDim.x;
    for (size_t k = (size_t)blockIdx.x * blockDim.x + threadIdx.x; k < nT; k += stride)
        E4[k] = (k < nU) ? u4[k] : i4[k - nU];
}

// ---------------- CSR build: per-row histogram ----------------
__global__ void hist_rows(const int* __restrict__ rows, int* __restrict__ cnt) {
    int stride = gridDim.x * blockDim.x;
    for (int e = blockIdx.x * blockDim.x + threadIdx.x; e < N_EDGES; e += stride)
        atomicAdd(&cnt[rows[e]], 1);
}

// exclusive scan within blocks of SCAN_BS; block totals to bsum
__global__ void scan_block(const int* __restrict__ cnt, int* __restrict__ excl,
                           int* __restrict__ bsum) {
    __shared__ int s[SCAN_BS];
    int tid = threadIdx.x;
    int i = blockIdx.x * SCAN_BS + tid;
    int x = (i < NN) ? cnt[i] : 0;
    s[tid] = x;
    __syncthreads();
    for (int off = 1; off < SCAN_BS; off <<= 1) {
        int t = (tid >= off) ? s[tid - off] : 0;
        __syncthreads();
        s[tid] += t;
        __syncthreads();
    }
    if (i < NN) excl[i] = s[tid] - x;
    if (tid == SCAN_BS - 1) bsum[blockIdx.x] = s[tid];
}

// exclusive scan of block sums (nb <= 512), single block of 512
__global__ void scan_bsum(int* __restrict__ bsum, int nb) {
    __shared__ int s[512];
    int tid = threadIdx.x;
    int x = (tid < nb) ? bsum[tid] : 0;
    s[tid] = x;
    __syncthreads();
    for (int off = 1; off < 512; off <<= 1) {
        int t = (tid >= off) ? s[tid - off] : 0;
        __syncthreads();
        s[tid] += t;
        __syncthreads();
    }
    if (tid < nb) bsum[tid] = s[tid] - x;
}

__global__ void add_offsets(int* __restrict__ rowptr, const int* __restrict__ bsum) {
    int i = blockIdx.x * blockDim.x + threadIdx.x;
    if (i < NN) rowptr[i] = rowptr[i] + bsum[i >> 10];
    if (i == 0) rowptr[NN] = N_EDGES;
}

// ---------------- pass 1: bin edges into 512-row buckets (coalesced runs) ----------------
__global__ void bin_pass1(const int* __restrict__ rows, const int* __restrict__ cols,
                          const float* __restrict__ vals, const int* __restrict__ rowptr,
                          int* __restrict__ gfill, int* __restrict__ erow,
                          int* __restrict__ ecol, float* __restrict__ eval) {
    __shared__ int hist[NB];
    __shared__ int goff[NB];
    __shared__ int lbs[NB];
    int tid = threadIdx.x;
    int e0 = blockIdx.x * CHUNK;
    int e1 = min(e0 + CHUNK, N_EDGES);
    for (int i = tid; i < NB; i += blockDim.x) {
        hist[i] = 0;
        lbs[i] = rowptr[i << BSHIFT];      // bucket base in the final CSR ordering
    }
    __syncthreads();
    for (int e = e0 + tid; e < e1; e += blockDim.x)
        atomicAdd(&hist[rows[e] >> BSHIFT], 1);
    __syncthreads();
    for (int i = tid; i < NB; i += blockDim.x) {
        int h = hist[i];
        goff[i] = h ? atomicAdd(&gfill[i], h) : 0;
        hist[i] = 0;                        // reuse as local rank counter
    }
    __syncthreads();
    for (int e = e0 + tid; e < e1; e += blockDim.x) {
        int r = rows[e];
        int b = r >> BSHIFT;
        int lr = atomicAdd(&hist[b], 1);
        int pos = lbs[b] + goff[b] + lr;
        erow[pos] = r;
        ecol[pos] = cols[e];
        eval[pos] = vals[e];
    }
}

// ---------------- pass 2: one workgroup per bucket, LDS tickets, L2-local writes ----------------
__global__ void bucket_scatter(const int* __restrict__ rowptr, const int* __restrict__ erow,
                               const int* __restrict__ ecol, const float* __restrict__ eval,
                               int2* __restrict__ epack) {
    __shared__ int lt[513];
    int b = blockIdx.x;
    int r0 = b << BSHIFT;
    int r1 = min(r0 + 512, NN);
    int nr = r1 - r0;
    int tid = threadIdx.x;
    for (int i = tid; i < nr; i += blockDim.x) lt[i] = rowptr[r0 + i];
    __syncthreads();
    int ebeg = rowptr[r0];
    int eend = rowptr[r1];
    for (int e = ebeg + tid; e < eend; e += blockDim.x) {
        int r = erow[e];
        int pos = atomicAdd(&lt[r - r0], 1);
        epack[pos] = make_int2(ecol[e], __float_as_int(eval[e]));
    }
}

// ---------------- SpMM: one wave per row, lane = dim, no atomics ----------------
__global__ void spmm_csr(const int* __restrict__ rowptr, const int2* __restrict__ ep,
                         const float* __restrict__ Ein, float* __restrict__ Eout) {
    int lane = threadIdx.x & 63;
    int w = (int)((blockIdx.x * (size_t)blockDim.x + threadIdx.x) >> 6);
    int row = __builtin_amdgcn_readfirstlane(w);
    if (row >= NN) return;
    int beg = rowptr[row];
    int end = rowptr[row + 1];
    float acc = 0.f;
    int j = beg;
    for (; j + 4 <= end; j += 4) {
        int2 e0 = ep[j], e1 = ep[j + 1], e2 = ep[j + 2], e3 = ep[j + 3];
        float x0 = Ein[(size_t)e0.x * DIM + lane];
        float x1 = Ein[(size_t)e1.x * DIM + lane];
        float x2 = Ein[(size_t)e2.x * DIM + lane];
        float x3 = Ein[(size_t)e3.x * DIM + lane];
        acc += __int_as_float(e0.y) * x0;
        acc += __int_as_float(e1.y) * x1;
        acc += __int_as_float(e2.y) * x2;
        acc += __int_as_float(e3.y) * x3;
    }
    for (; j < end; ++j) {
        int2 e = ep[j];
        acc += __int_as_float(e.y) * Ein[(size_t)e.x * DIM + lane];
    }
    Eout[(size_t)row * DIM + lane] = acc;
}

// ---------------- layer 3: SpMM only at the 2*BATCH target rows, fused acc ----------------
__global__ void spmm_target(const int* __restrict__ rowptr, const int2* __restrict__ ep,
                            const float* __restrict__ Ein, const int* __restrict__ U,
                            const int* __restrict__ I, float* __restrict__ accU,
                            float* __restrict__ accI) {
    int lane = threadIdx.x & 63;
    int w = (int)((blockIdx.x * (size_t)blockDim.x + threadIdx.x) >> 6);
    if (w >= 2 * BATCH) return;
    int row;
    float* accp;
    if (w < BATCH) { row = U[w];                 accp = accU + (size_t)w * DIM; }
    else           { row = N_USERS + I[w - BATCH]; accp = accI + (size_t)(w - BATCH) * DIM; }
    row = __builtin_amdgcn_readfirstlane(row);
    int beg = rowptr[row];
    int end = rowptr[row + 1];
    float acc = 0.f;
    int j = beg;
    for (; j + 4 <= end; j += 4) {
        int2 e0 = ep[j], e1 = ep[j + 1], e2 = ep[j + 2], e3 = ep[j + 3];
        acc += __int_as_float(e0.y) * Ein[(size_t)e0.x * DIM + lane];
        acc += __int_as_float(e1.y) * Ein[(size_t)e1.x * DIM + lane];
        acc += __int_as_float(e2.y) * Ein[(size_t)e2.x * DIM + lane];
        acc += __int_as_float(e3.y) * Ein[(size_t)e3.x * DIM + lane];
    }
    for (; j < end; ++j) {
        int2 e = ep[j];
        acc += __int_as_float(e.y) * Ein[(size_t)e.x * DIM + lane];
    }
    accp[lane] += acc;
}

// ---------------- acc at the 2*BATCH target rows ----------------
__global__ void acc_init(const float* __restrict__ E, const int* __restrict__ U,
                         const int* __restrict__ I, float* __restrict__ accU,
                         float* __restrict__ accI) {
    int t = blockIdx.x * blockDim.x + threadIdx.x;
    int b = t >> 6, d = t & 63;
    accU[t] = E[(size_t)U[b] * DIM + d];
    accI[t] = E[(size_t)(N_USERS + I[b]) * DIM + d];
}

__global__ void acc_add(const float* __restrict__ E, const int* __restrict__ U,
                        const int* __restrict__ I, float* __restrict__ accU,
                        float* __restrict__ accI) {
    int t = blockIdx.x * blockDim.x + threadIdx.x;
    int b = t >> 6, d = t & 63;
    accU[t] += E[(size_t)U[b] * DIM + d];
    accI[t] += E[(size_t)(N_USERS + I[b]) * DIM + d];
}

// ---------------- final: out[b] = dot(accU[b], accI[b]) / 16 ----------------
__global__ void dot_out(const float* __restrict__ accU, const float* __restrict__ accI,
                        float* __restrict__ out) {
    int t = blockIdx.x * blockDim.x + threadIdx.x;
    int b = t >> 6, lane = threadIdx.x & 63;
    float p = accU[t] * accI[t];
    #pragma unroll
    for (int off = 32; off; off >>= 1) p += __shfl_xor(p, off, 64);
    if (lane == 0) out[b] = p * (1.0f / 16.0f);
}

extern "C" void kernel_launch(void* const* d_in, const int* in_sizes, int n_in,
                              void* d_out, int out_size, void* d_ws, size_t ws_size,
                              hipStream_t stream) {
    const float* ue   = (const float*)d_in[0];
    const float* ie   = (const float*)d_in[1];
    const float* vals = (const float*)d_in[2];
    const int*   rows = (const int*)d_in[3];
    const int*   cols = (const int*)d_in[4];
    const int*   U    = (const int*)d_in[5];
    const int*   I    = (const int*)d_in[6];
    float* out = (float*)d_out;

    char* ws = (char*)d_ws;
    const size_t Ebytes  = (size_t)NN * DIM * sizeof(float);       // 76.8 MB
    const size_t EPbytes = (size_t)N_EDGES * sizeof(int2);         // 76.8 MB
    const size_t ACbytes = (size_t)BATCH * DIM * sizeof(float);    // 4.2 MB
    const size_t RPbytes = ((size_t)(NN + 1) * sizeof(int) + 255) & ~(size_t)255;

    size_t off = 0;
    float* Ecur   = (float*)(ws + off); off += Ebytes;             // region A (aliased by ebuf)
    float* Enext  = (float*)(ws + off); off += Ebytes;
    int2*  epack  = (int2*)(ws + off);  off += EPbytes;
    float* accU   = (float*)(ws + off); off += ACbytes;
    float* accI   = (float*)(ws + off); off += ACbytes;
    int*   rowptr = (int*)(ws + off);   off += RPbytes;
    int*   cnt    = (int*)(ws + off);   off += RPbytes;
    int*   gfill  = (int*)(ws + off);   off += ((NB * sizeof(int) + 255) & ~(size_t)255);
    int*   bsum   = (int*)(ws + off);   off += 512 * sizeof(int);

    // edge staging SoA aliases Ecur/Enext (dead before copy_init runs)
    int*   erow = (int*)ws;
    int*   ecol = erow + N_EDGES;
    float* eval = (float*)(ecol + N_EDGES);

    const int nScanBlocks = (NN + SCAN_BS - 1) / SCAN_BS;          // 293
    const int nBinBlocks  = (N_EDGES + CHUNK - 1) / CHUNK;         // 293

    // --- build CSR ---
    hipMemsetAsync(cnt, 0, RPbytes + (size_t)NB * sizeof(int), stream);  // cnt + gfill contiguous
    hist_rows<<<4096, 256, 0, stream>>>(rows, cnt);
    scan_block<<<nScanBlocks, SCAN_BS, 0, stream>>>(cnt, rowptr, bsum);
    scan_bsum<<<1, 512, 0, stream>>>(bsum, nScanBlocks);
    add_offsets<<<(NN + 255) / 256, 256, 0, stream>>>(rowptr, bsum);
    bin_pass1<<<nBinBlocks, 256, 0, stream>>>(rows, cols, vals, rowptr, gfill, erow, ecol, eval);
    bucket_scatter<<<NB, 256, 0, stream>>>(rowptr, erow, ecol, eval, epack);

    // --- embeddings + propagation ---
    copy_init<<<2048, 256, 0, stream>>>(ue, ie, Ecur);
    acc_init<<<BATCH * DIM / 256, 256, 0, stream>>>(Ecur, U, I, accU, accI);

    const int spmmBlocks = (NN * 64 + 255) / 256;                  // 1 wave per row
    for (int l = 0; l < 2; ++l) {
        spmm_csr<<<spmmBlocks, 256, 0, stream>>>(rowptr, epack, Ecur, Enext);
        acc_add<<<BATCH * DIM / 256, 256, 0, stream>>>(Enext, U, I, accU, accI);
        float* t = Ecur; Ecur = Enext; Enext = t;
    }
    spmm_target<<<2 * BATCH * 64 / 256, 256, 0, stream>>>(rowptr, epack, Ecur, U, I, accU, accI);

    dot_out<<<BATCH / 4, 256, 0, stream>>>(accU, accI, out);
}

// Round 4
// 1374.973 us; speedup vs baseline: 4.3470x; 1.3908x over previous
//
#include <hip/hip_runtime.h>

#define N_USERS 200000
#define N_ITEMS 100000
#define NN      300000        // N_USERS + N_ITEMS
#define DIM     64
#define N_EDGES 9600000
#define BATCH   16384
#define SCAN_BS 1024          // rows per scan block
#define BSH2    10            // 1024 rows per bucket
#define NB2     293           // ceil(NN / 1024)
#define CHUNK2  4096          // edges per bin_sort block

// ---------------- init: E0 = concat(user_emb, item_emb) ----------------
__global__ void copy_init(const float* __restrict__ ue, const float* __restrict__ ie,
                          float* __restrict__ E) {
    const size_t nU = (size_t)N_USERS * DIM / 4;
    const size_t nT = (size_t)NN * DIM / 4;
    const float4* u4 = (const float4*)ue;
    const float4* i4 = (const float4*)ie;
    float4* E4 = (float4*)E;
    size_t stride = (size_t)gridDim.x * blockDim.x;
    for (size_t k = (size_t)blockIdx.x * blockDim.x + threadIdx.x; k < nT; k += stride)
        E4[k] = (k < nU) ? u4[k] : i4[k - nU];
}

// ---------------- CSR build: per-row histogram ----------------
__global__ void hist_rows(const int* __restrict__ rows, int* __restrict__ cnt) {
    int stride = gridDim.x * blockDim.x;
    for (int e = blockIdx.x * blockDim.x + threadIdx.x; e < N_EDGES; e += stride)
        atomicAdd(&cnt[rows[e]], 1);
}

// exclusive scan within blocks of SCAN_BS; block totals to bsum
__global__ void scan_block(const int* __restrict__ cnt, int* __restrict__ excl,
                           int* __restrict__ bsum) {
    __shared__ int s[SCAN_BS];
    int tid = threadIdx.x;
    int i = blockIdx.x * SCAN_BS + tid;
    int x = (i < NN) ? cnt[i] : 0;
    s[tid] = x;
    __syncthreads();
    for (int off = 1; off < SCAN_BS; off <<= 1) {
        int t = (tid >= off) ? s[tid - off] : 0;
        __syncthreads();
        s[tid] += t;
        __syncthreads();
    }
    if (i < NN) excl[i] = s[tid] - x;
    if (tid == SCAN_BS - 1) bsum[blockIdx.x] = s[tid];
}

// exclusive scan of block sums (nb <= 512), single block of 512
__global__ void scan_bsum(int* __restrict__ bsum, int nb) {
    __shared__ int s[512];
    int tid = threadIdx.x;
    int x = (tid < nb) ? bsum[tid] : 0;
    s[tid] = x;
    __syncthreads();
    for (int off = 1; off < 512; off <<= 1) {
        int t = (tid >= off) ? s[tid - off] : 0;
        __syncthreads();
        s[tid] += t;
        __syncthreads();
    }
    if (tid < nb) bsum[tid] = s[tid] - x;
}

__global__ void add_offsets(int* __restrict__ rowptr, const int* __restrict__ bsum) {
    int i = blockIdx.x * blockDim.x + threadIdx.x;
    if (i < NN) rowptr[i] = rowptr[i] + bsum[i >> 10];
    if (i == 0) rowptr[NN] = N_EDGES;
}

__global__ void init_gfill(const int* __restrict__ rowptr, int* __restrict__ gfill) {
    int i = blockIdx.x * blockDim.x + threadIdx.x;
    if (i < NB2) gfill[i] = rowptr[i << BSH2];
}

// ---------------- pass 1: per-block counting sort by 1024-row bucket ----------------
// Reorders edges in LDS so global stores are consecutive within each bucket run
// (wave-contiguous -> no partial-line write amplification). Staged edge is packed
// int2: (row_local<<19 | col, val) = 8 B.
__global__ __launch_bounds__(256) void bin_sort(const int* __restrict__ rows,
                                                const int* __restrict__ cols,
                                                const float* __restrict__ vals,
                                                int* __restrict__ gfill,
                                                int2* __restrict__ estage) {
    __shared__ int  hist[NB2 + 1];
    __shared__ int  sc[NB2 + 1];     // inclusive scan, then overwritten with exclusive
    __shared__ int  gbase[NB2];
    __shared__ int  rankc[NB2];
    __shared__ int2 st[CHUNK2];
    __shared__ int  dstb[CHUNK2];

    int tid = threadIdx.x;
    int e0 = blockIdx.x * CHUNK2;
    int e1 = min(e0 + CHUNK2, N_EDGES);
    int n  = e1 - e0;

    for (int i = tid; i <= NB2; i += 256) { hist[i] = 0; sc[i] = 0; }
    __syncthreads();

    for (int e = e0 + tid; e < e1; e += 256)
        atomicAdd(&hist[rows[e] >> BSH2], 1);
    __syncthreads();

    for (int i = tid; i < NB2; i += 256) sc[i] = hist[i];
    __syncthreads();

    // inclusive Hillis-Steele scan over NB2 entries, 256 threads own 2 slots each
    for (int off = 1; off < NB2; off <<= 1) {
        int i0 = tid, i1 = tid + 256;
        int a0 = 0, a1 = 0;
        if (i0 < NB2 && i0 >= off) a0 = sc[i0 - off];
        if (i1 < NB2 && i1 >= off) a1 = sc[i1 - off];
        __syncthreads();
        if (i0 < NB2 && i0 >= off) sc[i0] += a0;
        if (i1 < NB2 && i1 >= off) sc[i1] += a1;
        __syncthreads();
    }

    // reserve global runs; convert sc to exclusive (own-slot ops only)
    for (int b = tid; b < NB2; b += 256) {
        int cb = hist[b];
        sc[b] = sc[b] - cb;                       // exclusive start within block
        gbase[b] = cb ? atomicAdd(&gfill[b], cb) : 0;
        rankc[b] = 0;
    }
    __syncthreads();

    // rank + reorder into LDS
    for (int e = e0 + tid; e < e1; e += 256) {
        int r = rows[e];
        int c = cols[e];
        float v = vals[e];
        int b = r >> BSH2;
        int lr = atomicAdd(&rankc[b], 1);
        int lpos = sc[b] + lr;
        st[lpos]   = make_int2(((r & 1023) << 19) | c, __float_as_int(v));
        dstb[lpos] = gbase[b] + lr;
    }
    __syncthreads();

    // flush: LDS order is bucket-grouped -> consecutive global addresses per run
    for (int i = tid; i < n; i += 256)
        estage[dstb[i]] = st[i];
}

// ---------------- pass 2: one block per bucket, LDS row tickets, L2-local window ----------------
__global__ __launch_bounds__(1024) void row_scatter(const int* __restrict__ rowptr,
                                                    const int2* __restrict__ estage,
                                                    int2* __restrict__ epack) {
    __shared__ int lt[1024];
    int b = blockIdx.x;
    int r0 = b << BSH2;
    int r1 = min(r0 + 1024, NN);
    int nr = r1 - r0;
    int tid = threadIdx.x;
    for (int i = tid; i < nr; i += 1024) lt[i] = rowptr[r0 + i];
    __syncthreads();
    int ebeg = rowptr[r0];
    int eend = rowptr[r1];
    for (int e = ebeg + tid; e < eend; e += 1024) {
        int2 ed = estage[e];
        int rl = ((unsigned)ed.x) >> 19;
        int pos = atomicAdd(&lt[rl], 1);
        epack[pos] = make_int2(ed.x & 0x7FFFF, ed.y);
    }
}

// ---------------- SpMM: one wave per row, lane = dim, no atomics ----------------
__global__ void spmm_csr(const int* __restrict__ rowptr, const int2* __restrict__ ep,
                         const float* __restrict__ Ein, float* __restrict__ Eout) {
    int lane = threadIdx.x & 63;
    int w = (int)((blockIdx.x * (size_t)blockDim.x + threadIdx.x) >> 6);
    int row = __builtin_amdgcn_readfirstlane(w);
    if (row >= NN) return;
    int beg = rowptr[row];
    int end = rowptr[row + 1];
    float acc = 0.f;
    int j = beg;
    for (; j + 4 <= end; j += 4) {
        int2 e0 = ep[j], e1 = ep[j + 1], e2 = ep[j + 2], e3 = ep[j + 3];
        float x0 = Ein[(size_t)e0.x * DIM + lane];
        float x1 = Ein[(size_t)e1.x * DIM + lane];
        float x2 = Ein[(size_t)e2.x * DIM + lane];
        float x3 = Ein[(size_t)e3.x * DIM + lane];
        acc += __int_as_float(e0.y) * x0;
        acc += __int_as_float(e1.y) * x1;
        acc += __int_as_float(e2.y) * x2;
        acc += __int_as_float(e3.y) * x3;
    }
    for (; j < end; ++j) {
        int2 e = ep[j];
        acc += __int_as_float(e.y) * Ein[(size_t)e.x * DIM + lane];
    }
    Eout[(size_t)row * DIM + lane] = acc;
}

// ---------------- layer 3: SpMM only at the 2*BATCH target rows, fused acc ----------------
__global__ void spmm_target(const int* __restrict__ rowptr, const int2* __restrict__ ep,
                            const float* __restrict__ Ein, const int* __restrict__ U,
                            const int* __restrict__ I, float* __restrict__ accU,
                            float* __restrict__ accI) {
    int lane = threadIdx.x & 63;
    int w = (int)((blockIdx.x * (size_t)blockDim.x + threadIdx.x) >> 6);
    if (w >= 2 * BATCH) return;
    int row;
    float* accp;
    if (w < BATCH) { row = U[w];                   accp = accU + (size_t)w * DIM; }
    else           { row = N_USERS + I[w - BATCH]; accp = accI + (size_t)(w - BATCH) * DIM; }
    row = __builtin_amdgcn_readfirstlane(row);
    int beg = rowptr[row];
    int end = rowptr[row + 1];
    float acc = 0.f;
    int j = beg;
    for (; j + 4 <= end; j += 4) {
        int2 e0 = ep[j], e1 = ep[j + 1], e2 = ep[j + 2], e3 = ep[j + 3];
        acc += __int_as_float(e0.y) * Ein[(size_t)e0.x * DIM + lane];
        acc += __int_as_float(e1.y) * Ein[(size_t)e1.x * DIM + lane];
        acc += __int_as_float(e2.y) * Ein[(size_t)e2.x * DIM + lane];
        acc += __int_as_float(e3.y) * Ein[(size_t)e3.x * DIM + lane];
    }
    for (; j < end; ++j) {
        int2 e = ep[j];
        acc += __int_as_float(e.y) * Ein[(size_t)e.x * DIM + lane];
    }
    accp[lane] += acc;
}

// ---------------- acc at the 2*BATCH target rows ----------------
__global__ void acc_init(const float* __restrict__ E, const int* __restrict__ U,
                         const int* __restrict__ I, float* __restrict__ accU,
                         float* __restrict__ accI) {
    int t = blockIdx.x * blockDim.x + threadIdx.x;
    int b = t >> 6, d = t & 63;
    accU[t] = E[(size_t)U[b] * DIM + d];
    accI[t] = E[(size_t)(N_USERS + I[b]) * DIM + d];
}

__global__ void acc_add(const float* __restrict__ E, const int* __restrict__ U,
                        const int* __restrict__ I, float* __restrict__ accU,
                        float* __restrict__ accI) {
    int t = blockIdx.x * blockDim.x + threadIdx.x;
    int b = t >> 6, d = t & 63;
    accU[t] += E[(size_t)U[b] * DIM + d];
    accI[t] += E[(size_t)(N_USERS + I[b]) * DIM + d];
}

// ---------------- final: out[b] = dot(accU[b], accI[b]) / 16 ----------------
__global__ void dot_out(const float* __restrict__ accU, const float* __restrict__ accI,
                        float* __restrict__ out) {
    int t = blockIdx.x * blockDim.x + threadIdx.x;
    int b = t >> 6, lane = threadIdx.x & 63;
    float p = accU[t] * accI[t];
    #pragma unroll
    for (int off = 32; off; off >>= 1) p += __shfl_xor(p, off, 64);
    if (lane == 0) out[b] = p * (1.0f / 16.0f);
}

extern "C" void kernel_launch(void* const* d_in, const int* in_sizes, int n_in,
                              void* d_out, int out_size, void* d_ws, size_t ws_size,
                              hipStream_t stream) {
    const float* ue   = (const float*)d_in[0];
    const float* ie   = (const float*)d_in[1];
    const float* vals = (const float*)d_in[2];
    const int*   rows = (const int*)d_in[3];
    const int*   cols = (const int*)d_in[4];
    const int*   U    = (const int*)d_in[5];
    const int*   I    = (const int*)d_in[6];
    float* out = (float*)d_out;

    char* ws = (char*)d_ws;
    const size_t Ebytes  = (size_t)NN * DIM * sizeof(float);       // 76.8 MB
    const size_t EPbytes = (size_t)N_EDGES * sizeof(int2);         // 76.8 MB
    const size_t ACbytes = (size_t)BATCH * DIM * sizeof(float);    // 4.2 MB
    const size_t RPbytes = ((size_t)(NN + 1) * sizeof(int) + 255) & ~(size_t)255;

    size_t off = 0;
    float* Ecur   = (float*)(ws + off); off += Ebytes;             // aliased by estage pre-copy_init
    float* Enext  = (float*)(ws + off); off += Ebytes;
    int2*  epack  = (int2*)(ws + off);  off += EPbytes;
    float* accU   = (float*)(ws + off); off += ACbytes;
    float* accI   = (float*)(ws + off); off += ACbytes;
    int*   rowptr = (int*)(ws + off);   off += RPbytes;
    int*   cnt    = (int*)(ws + off);   off += RPbytes;
    int*   gfill  = (int*)(ws + off);   off += ((NB2 * sizeof(int) + 255) & ~(size_t)255);
    int*   bsum   = (int*)(ws + off);   off += 512 * sizeof(int);

    // edge staging (8 B/edge) aliases Ecur region (dead before copy_init runs)
    int2* estage = (int2*)ws;

    const int nScanBlocks = (NN + SCAN_BS - 1) / SCAN_BS;          // 293
    const int nBinBlocks  = (N_EDGES + CHUNK2 - 1) / CHUNK2;       // 2344

    // --- build CSR ---
    hipMemsetAsync(cnt, 0, (size_t)NN * sizeof(int), stream);
    hist_rows<<<4096, 256, 0, stream>>>(rows, cnt);
    scan_block<<<nScanBlocks, SCAN_BS, 0, stream>>>(cnt, rowptr, bsum);
    scan_bsum<<<1, 512, 0, stream>>>(bsum, nScanBlocks);
    add_offsets<<<(NN + 255) / 256, 256, 0, stream>>>(rowptr, bsum);
    init_gfill<<<(NB2 + 255) / 256, 256, 0, stream>>>(rowptr, gfill);
    bin_sort<<<nBinBlocks, 256, 0, stream>>>(rows, cols, vals, gfill, estage);
    row_scatter<<<NB2, 1024, 0, stream>>>(rowptr, estage, epack);

    // --- embeddings + propagation ---
    copy_init<<<2048, 256, 0, stream>>>(ue, ie, Ecur);
    acc_init<<<BATCH * DIM / 256, 256, 0, stream>>>(Ecur, U, I, accU, accI);

    const int spmmBlocks = (NN * 64 + 255) / 256;                  // 1 wave per row
    for (int l = 0; l < 2; ++l) {
        spmm_csr<<<spmmBlocks, 256, 0, stream>>>(rowptr, epack, Ecur, Enext);
        acc_add<<<BATCH * DIM / 256, 256, 0, stream>>>(Enext, U, I, accU, accI);
        float* t = Ecur; Ecur = Enext; Enext = t;
    }
    spmm_target<<<2 * BATCH * 64 / 256, 256, 0, stream>>>(rowptr, epack, Ecur, U, I, accU, accI);

    dot_out<<<BATCH / 4, 256, 0, stream>>>(accU, accI, out);
}

// Round 5
// 1049.844 us; speedup vs baseline: 5.6932x; 1.3097x over previous
//
#include <hip/hip_runtime.h>

#define N_USERS 200000
#define N_ITEMS 100000
#define NN      300000        // N_USERS + N_ITEMS
#define DIM     64
#define N_EDGES 9600000
#define BATCH   16384
#define BSH2    10            // 1024 rows per bucket
#define NB2     293           // ceil(NN / 1024)
#define CHUNK2  4096          // edges per bin_sort block

// ---------------- init: E0 = concat(user_emb, item_emb) ----------------
__global__ void copy_init(const float* __restrict__ ue, const float* __restrict__ ie,
                          float* __restrict__ E) {
    const size_t nU = (size_t)N_USERS * DIM / 4;
    const size_t nT = (size_t)NN * DIM / 4;
    const float4* u4 = (const float4*)ue;
    const float4* i4 = (const float4*)ie;
    float4* E4 = (float4*)E;
    size_t stride = (size_t)gridDim.x * blockDim.x;
    for (size_t k = (size_t)blockIdx.x * blockDim.x + threadIdx.x; k < nT; k += stride)
        E4[k] = (k < nU) ? u4[k] : i4[k - nU];
}

// ---------------- bucket-level histogram (LDS-staged, ~300K global adds total) ----------------
__global__ void hist_buckets(const int* __restrict__ rows, int* __restrict__ bcnt) {
    __shared__ int h[NB2];
    for (int i = threadIdx.x; i < NB2; i += blockDim.x) h[i] = 0;
    __syncthreads();
    int stride = gridDim.x * blockDim.x;
    for (int e = blockIdx.x * blockDim.x + threadIdx.x; e < N_EDGES; e += stride)
        atomicAdd(&h[rows[e] >> BSH2], 1);
    __syncthreads();
    for (int i = threadIdx.x; i < NB2; i += blockDim.x)
        if (h[i]) atomicAdd(&bcnt[i], h[i]);
}

// exclusive scan of 293 bucket counts; writes bstart[] and seeds gfill[]
__global__ void scan_buckets(const int* __restrict__ bcnt, int* __restrict__ bstart,
                             int* __restrict__ gfill) {
    __shared__ int s[512];
    int tid = threadIdx.x;
    int x = (tid < NB2) ? bcnt[tid] : 0;
    s[tid] = x;
    __syncthreads();
    for (int off = 1; off < 512; off <<= 1) {
        int t = (tid >= off) ? s[tid - off] : 0;
        __syncthreads();
        s[tid] += t;
        __syncthreads();
    }
    if (tid < NB2) { int v = s[tid] - x; bstart[tid] = v; gfill[tid] = v; }
    if (tid == 0) bstart[NB2] = N_EDGES;
}

// ---------------- pass 1: per-block counting sort by 1024-row bucket ----------------
// Reorders edges in LDS so global stores are consecutive within each bucket run.
// Staged edge is packed int2: (row_local<<19 | col, val) = 8 B.
__global__ __launch_bounds__(256) void bin_sort(const int* __restrict__ rows,
                                                const int* __restrict__ cols,
                                                const float* __restrict__ vals,
                                                int* __restrict__ gfill,
                                                int2* __restrict__ estage) {
    __shared__ int  hist[NB2 + 1];
    __shared__ int  sc[NB2 + 1];
    __shared__ int  gbase[NB2];
    __shared__ int  rankc[NB2];
    __shared__ int2 st[CHUNK2];
    __shared__ int  dstb[CHUNK2];

    int tid = threadIdx.x;
    int e0 = blockIdx.x * CHUNK2;
    int e1 = min(e0 + CHUNK2, N_EDGES);
    int n  = e1 - e0;

    for (int i = tid; i <= NB2; i += 256) { hist[i] = 0; sc[i] = 0; }
    __syncthreads();

    for (int e = e0 + tid; e < e1; e += 256)
        atomicAdd(&hist[rows[e] >> BSH2], 1);
    __syncthreads();

    for (int i = tid; i < NB2; i += 256) sc[i] = hist[i];
    __syncthreads();

    // inclusive Hillis-Steele scan over NB2 entries (256 threads own 2 slots each)
    for (int off = 1; off < NB2; off <<= 1) {
        int i0 = tid, i1 = tid + 256;
        int a0 = 0, a1 = 0;
        if (i0 < NB2 && i0 >= off) a0 = sc[i0 - off];
        if (i1 < NB2 && i1 >= off) a1 = sc[i1 - off];
        __syncthreads();
        if (i0 < NB2 && i0 >= off) sc[i0] += a0;
        if (i1 < NB2 && i1 >= off) sc[i1] += a1;
        __syncthreads();
    }

    for (int b = tid; b < NB2; b += 256) {
        int cb = hist[b];
        sc[b] = sc[b] - cb;                       // exclusive start within block
        gbase[b] = cb ? atomicAdd(&gfill[b], cb) : 0;
        rankc[b] = 0;
    }
    __syncthreads();

    for (int e = e0 + tid; e < e1; e += 256) {
        int r = rows[e];
        int c = cols[e];
        float v = vals[e];
        int b = r >> BSH2;
        int lr = atomicAdd(&rankc[b], 1);
        int lpos = sc[b] + lr;
        st[lpos]   = make_int2(((r & 1023) << 19) | c, __float_as_int(v));
        dstb[lpos] = gbase[b] + lr;
    }
    __syncthreads();

    for (int i = tid; i < n; i += 256)
        estage[dstb[i]] = st[i];
}

// ---------------- pass 2: one block per bucket; builds per-row rowptr in LDS,
// then ticket-scatters into the final CSR order (L2-local 256 KB window) ----------------
__global__ __launch_bounds__(1024) void row_scatter(const int* __restrict__ bstart,
                                                    const int2* __restrict__ estage,
                                                    int2* __restrict__ epack,
                                                    int* __restrict__ rowptr) {
    __shared__ int lcnt[1024];
    __shared__ int s[1024];
    int b = blockIdx.x;
    int r0 = b << BSH2;
    int nr = min(1024, NN - r0);
    int tid = threadIdx.x;
    lcnt[tid] = 0;
    __syncthreads();

    int ebeg = bstart[b];
    int eend = bstart[b + 1];
    for (int e = ebeg + tid; e < eend; e += 1024)
        atomicAdd(&lcnt[((unsigned)estage[e].x) >> 19], 1);
    __syncthreads();

    // exclusive scan of the 1024 per-row counts
    int x = lcnt[tid];
    s[tid] = x;
    __syncthreads();
    for (int off = 1; off < 1024; off <<= 1) {
        int t = (tid >= off) ? s[tid - off] : 0;
        __syncthreads();
        s[tid] += t;
        __syncthreads();
    }
    int myptr = ebeg + s[tid] - x;
    if (tid < nr) rowptr[r0 + tid] = myptr;
    lcnt[tid] = myptr;                 // reuse as ticket
    __syncthreads();

    for (int e = ebeg + tid; e < eend; e += 1024) {
        int2 ed = estage[e];
        int rl = ((unsigned)ed.x) >> 19;
        int pos = atomicAdd(&lcnt[rl], 1);
        epack[pos] = make_int2(ed.x & 0x7FFFF, ed.y);
    }
    if (b == 0 && tid == 0) rowptr[NN] = N_EDGES;
}

// ---------------- SpMM: one wave per row, lane = dim, no atomics ----------------
__global__ void spmm_csr(const int* __restrict__ rowptr, const int2* __restrict__ ep,
                         const float* __restrict__ Ein, float* __restrict__ Eout) {
    int lane = threadIdx.x & 63;
    int w = (int)((blockIdx.x * (size_t)blockDim.x + threadIdx.x) >> 6);
    int row = __builtin_amdgcn_readfirstlane(w);
    if (row >= NN) return;
    int beg = rowptr[row];
    int end = rowptr[row + 1];
    float acc = 0.f;
    int j = beg;
    for (; j + 4 <= end; j += 4) {
        int2 e0 = ep[j], e1 = ep[j + 1], e2 = ep[j + 2], e3 = ep[j + 3];
        float x0 = Ein[(size_t)e0.x * DIM + lane];
        float x1 = Ein[(size_t)e1.x * DIM + lane];
        float x2 = Ein[(size_t)e2.x * DIM + lane];
        float x3 = Ein[(size_t)e3.x * DIM + lane];
        acc += __int_as_float(e0.y) * x0;
        acc += __int_as_float(e1.y) * x1;
        acc += __int_as_float(e2.y) * x2;
        acc += __int_as_float(e3.y) * x3;
    }
    for (; j < end; ++j) {
        int2 e = ep[j];
        acc += __int_as_float(e.y) * Ein[(size_t)e.x * DIM + lane];
    }
    Eout[(size_t)row * DIM + lane] = acc;
}

// ---------------- layer 3: SpMM only at the 2*BATCH target rows, fused acc ----------------
__global__ void spmm_target(const int* __restrict__ rowptr, const int2* __restrict__ ep,
                            const float* __restrict__ Ein, const int* __restrict__ U,
                            const int* __restrict__ I, float* __restrict__ accU,
                            float* __restrict__ accI) {
    int lane = threadIdx.x & 63;
    int w = (int)((blockIdx.x * (size_t)blockDim.x + threadIdx.x) >> 6);
    if (w >= 2 * BATCH) return;
    int row;
    float* accp;
    if (w < BATCH) { row = U[w];                   accp = accU + (size_t)w * DIM; }
    else           { row = N_USERS + I[w - BATCH]; accp = accI + (size_t)(w - BATCH) * DIM; }
    row = __builtin_amdgcn_readfirstlane(row);
    int beg = rowptr[row];
    int end = rowptr[row + 1];
    float acc = 0.f;
    int j = beg;
    for (; j + 4 <= end; j += 4) {
        int2 e0 = ep[j], e1 = ep[j + 1], e2 = ep[j + 2], e3 = ep[j + 3];
        acc += __int_as_float(e0.y) * Ein[(size_t)e0.x * DIM + lane];
        acc += __int_as_float(e1.y) * Ein[(size_t)e1.x * DIM + lane];
        acc += __int_as_float(e2.y) * Ein[(size_t)e2.x * DIM + lane];
        acc += __int_as_float(e3.y) * Ein[(size_t)e3.x * DIM + lane];
    }
    for (; j < end; ++j) {
        int2 e = ep[j];
        acc += __int_as_float(e.y) * Ein[(size_t)e.x * DIM + lane];
    }
    accp[lane] += acc;
}

// ---------------- acc at the 2*BATCH target rows ----------------
__global__ void acc_init(const float* __restrict__ E, const int* __restrict__ U,
                         const int* __restrict__ I, float* __restrict__ accU,
                         float* __restrict__ accI) {
    int t = blockIdx.x * blockDim.x + threadIdx.x;
    int b = t >> 6, d = t & 63;
    accU[t] = E[(size_t)U[b] * DIM + d];
    accI[t] = E[(size_t)(N_USERS + I[b]) * DIM + d];
}

__global__ void acc_add(const float* __restrict__ E, const int* __restrict__ U,
                        const int* __restrict__ I, float* __restrict__ accU,
                        float* __restrict__ accI) {
    int t = blockIdx.x * blockDim.x + threadIdx.x;
    int b = t >> 6, d = t & 63;
    accU[t] += E[(size_t)U[b] * DIM + d];
    accI[t] += E[(size_t)(N_USERS + I[b]) * DIM + d];
}

// ---------------- final: out[b] = dot(accU[b], accI[b]) / 16 ----------------
__global__ void dot_out(const float* __restrict__ accU, const float* __restrict__ accI,
                        float* __restrict__ out) {
    int t = blockIdx.x * blockDim.x + threadIdx.x;
    int b = t >> 6, lane = threadIdx.x & 63;
    float p = accU[t] * accI[t];
    #pragma unroll
    for (int off = 32; off; off >>= 1) p += __shfl_xor(p, off, 64);
    if (lane == 0) out[b] = p * (1.0f / 16.0f);
}

extern "C" void kernel_launch(void* const* d_in, const int* in_sizes, int n_in,
                              void* d_out, int out_size, void* d_ws, size_t ws_size,
                              hipStream_t stream) {
    const float* ue   = (const float*)d_in[0];
    const float* ie   = (const float*)d_in[1];
    const float* vals = (const float*)d_in[2];
    const int*   rows = (const int*)d_in[3];
    const int*   cols = (const int*)d_in[4];
    const int*   U    = (const int*)d_in[5];
    const int*   I    = (const int*)d_in[6];
    float* out = (float*)d_out;

    char* ws = (char*)d_ws;
    const size_t Ebytes  = (size_t)NN * DIM * sizeof(float);       // 76.8 MB
    const size_t EPbytes = (size_t)N_EDGES * sizeof(int2);         // 76.8 MB
    const size_t ACbytes = (size_t)BATCH * DIM * sizeof(float);    // 4.2 MB
    const size_t RPbytes = ((size_t)(NN + 1) * sizeof(int) + 255) & ~(size_t)255;
    const size_t NBbytes = (((size_t)(NB2 + 1) * sizeof(int)) + 255) & ~(size_t)255;

    size_t off = 0;
    float* Ecur   = (float*)(ws + off); off += Ebytes;             // aliased by estage pre-copy_init
    float* Enext  = (float*)(ws + off); off += Ebytes;
    int2*  epack  = (int2*)(ws + off);  off += EPbytes;
    float* accU   = (float*)(ws + off); off += ACbytes;
    float* accI   = (float*)(ws + off); off += ACbytes;
    int*   rowptr = (int*)(ws + off);   off += RPbytes;
    int*   bcnt   = (int*)(ws + off);   off += NBbytes;
    int*   bstart = (int*)(ws + off);   off += NBbytes;
    int*   gfill  = (int*)(ws + off);   off += NBbytes;

    // edge staging (8 B/edge) aliases Ecur/Enext region (dead before copy_init runs)
    int2* estage = (int2*)ws;

    const int nBinBlocks = (N_EDGES + CHUNK2 - 1) / CHUNK2;        // 2344

    // --- build CSR (no per-row global histogram) ---
    hipMemsetAsync(bcnt, 0, (size_t)(NB2 + 1) * sizeof(int), stream);
    hist_buckets<<<1024, 256, 0, stream>>>(rows, bcnt);
    scan_buckets<<<1, 512, 0, stream>>>(bcnt, bstart, gfill);
    bin_sort<<<nBinBlocks, 256, 0, stream>>>(rows, cols, vals, gfill, estage);
    row_scatter<<<NB2, 1024, 0, stream>>>(bstart, estage, epack, rowptr);

    // --- embeddings + propagation ---
    copy_init<<<2048, 256, 0, stream>>>(ue, ie, Ecur);
    acc_init<<<BATCH * DIM / 256, 256, 0, stream>>>(Ecur, U, I, accU, accI);

    const int spmmBlocks = (NN * 64 + 255) / 256;                  // 1 wave per row
    for (int l = 0; l < 2; ++l) {
        spmm_csr<<<spmmBlocks, 256, 0, stream>>>(rowptr, epack, Ecur, Enext);
        acc_add<<<BATCH * DIM / 256, 256, 0, stream>>>(Enext, U, I, accU, accI);
        float* t = Ecur; Ecur = Enext; Enext = t;
    }
    spmm_target<<<2 * BATCH * 64 / 256, 256, 0, stream>>>(rowptr, epack, Ecur, U, I, accU, accI);

    dot_out<<<BATCH / 4, 256, 0, stream>>>(accU, accI, out);
}